// Round 1
// baseline (557.905 us; speedup 1.0000x reference)
//
#include <hip/hip_runtime.h>

typedef float f32x4 __attribute__((ext_vector_type(4)));
typedef __bf16 bf16x8 __attribute__((ext_vector_type(8)));

#define DEV_INLINE __device__ __forceinline__

constexpr int B_N  = 2;
constexpr int C3_N = 128;
constexpr int C2_N = 96;
constexpr int DZ_N = 32;
constexpr int H_N  = 24;
constexpr int W_N  = 24;
constexpr int K_N  = 8;
constexpr int E_N  = 256;
constexpr int HW_N = 576;

DEV_INLINE unsigned short f2bf(float x) {
  union { float f; unsigned u; } v; v.f = x;
  unsigned r = v.u + 0x7FFFu + ((v.u >> 16) & 1u);
  return (unsigned short)(r >> 16);
}

// ---------------------------------------------------------------------------
// Topo kernel A: partial 3x3 conv (C2->64), split over 4 c-chunks of 24.
// grid 256 = (bk 16) x (tg 4: 16 t each) x (cc 4: 24 c each), 384 threads.
// Thread = (y 0..23, tq 0..15): one output row (24 x) for one hidden t.
// ---------------------------------------------------------------------------
__global__ __launch_bounds__(384) void topo_conv1(
    const float* __restrict__ F2, const float* __restrict__ W1,
    float* __restrict__ Hp) {
  const int bid = blockIdx.x;
  const int cc = bid & 3;
  const int tg = (bid >> 2) & 3;
  const int bk = bid >> 4;           // 0..15 = b*8 + k
  const int b = bk >> 3, k = bk & 7;
  const int tid = threadIdx.x;
  const int y = tid >> 4;            // 0..23
  const int tq = tid & 15;           // 0..15

  __shared__ float simg[8][26][28];  // padded image chunk (8 channels)
  __shared__ float sw[16 * 97];      // weights: [tq][c*12+q], stride 97 vs bank conflicts

  float acc[24];
#pragma unroll
  for (int i = 0; i < 24; i++) acc[i] = 0.f;

  float* simgf = &simg[0][0][0];
  for (int i = tid; i < 8 * 26 * 28; i += 384) simgf[i] = 0.f;
  __syncthreads();

  for (int ch = 0; ch < 3; ch++) {
    if (ch) __syncthreads();
    const int c0 = cc * 24 + ch * 8;
    for (int i = tid; i < 8 * 24 * 24; i += 384) {
      int c = i / 576, p = i - c * 576;
      int yy = p / 24, xx = p - yy * 24;
      simg[c][yy + 1][xx + 1] =
          F2[(((b * C2_N + c0 + c) * H_N + yy) * W_N + xx) * K_N + k];
    }
    for (int i = tid; i < 16 * 72; i += 384) {
      int t2 = i / 72, rest = i - t2 * 72;
      int c = rest / 9, q = rest - c * 9;
      sw[t2 * 97 + c * 12 + q] =
          W1[(tg * 16 + t2) * (C2_N * 9) + (c0 + c) * 9 + q];
    }
    __syncthreads();
#pragma unroll 1
    for (int c = 0; c < 8; c++) {
      float w[9];
#pragma unroll
      for (int q = 0; q < 9; q++) w[q] = sw[tq * 97 + c * 12 + q];
#pragma unroll
      for (int dy = 0; dy < 3; dy++) {
        float r[26];
#pragma unroll
        for (int xx = 0; xx < 26; xx++) r[xx] = simg[c][y + dy][xx];
#pragma unroll
        for (int dx = 0; dx < 3; dx++) {
          float wv = w[dy * 3 + dx];
#pragma unroll
          for (int xx = 0; xx < 24; xx++)
            acc[xx] = fmaf(wv, r[xx + dx], acc[xx]);
        }
      }
    }
  }
  const int t = tg * 16 + tq;
  float* dst = &Hp[((cc * 16 + bk) * 64 + t) * HW_N + y * 24];
#pragma unroll
  for (int xx = 0; xx < 24; xx++) dst[xx] = acc[xx];
}

// ---------------------------------------------------------------------------
// Topo kernel B: sum c-chunk partials, bn+relu, 1x1 conv, neighbor sum.
// grid 16 (bk), 576 threads (one per pixel).
// ---------------------------------------------------------------------------
__global__ __launch_bounds__(576) void topo_final(
    const float* __restrict__ Hp, const float* __restrict__ bn_g,
    const float* __restrict__ bn_b, const float* __restrict__ W2,
    const float* __restrict__ b2, float* __restrict__ topo) {
  const int bk = blockIdx.x;
  const int p = threadIdx.x;
  __shared__ float pp[26][28];
  float* ppf = &pp[0][0];
  for (int i = p; i < 26 * 28; i += 576) ppf[i] = 0.f;

  const float inv = rsqrtf(1.0f + 1e-5f);  // bn uses sqrt(1.0+EPS) exactly
  float acc = b2[0];
  for (int t = 0; t < 64; t++) {
    float v = 0.f;
#pragma unroll
    for (int c4 = 0; c4 < 4; c4++)
      v += Hp[((c4 * 16 + bk) * 64 + t) * HW_N + p];
    float hcv = fmaxf(fmaf(bn_g[t] * inv, v, bn_b[t]), 0.f);
    acc = fmaf(W2[t], hcv, acc);
  }
  __syncthreads();
  pp[p / 24 + 1][p % 24 + 1] = acc;
  __syncthreads();
  const int yy = p / 24 + 1, xx = p % 24 + 1;
  float s = pp[yy-1][xx-1] + pp[yy-1][xx] + pp[yy-1][xx+1]
          + pp[yy][xx-1]                  + pp[yy][xx+1]
          + pp[yy+1][xx-1] + pp[yy+1][xx] + pp[yy+1][xx+1];
  topo[bk * HW_N + p] = acc + 0.5f * s;
}

// ---------------------------------------------------------------------------
// Projection GEMM: out[row][256] = A[row][CIN] @ W[CIN][256], fp32 vector.
// A[row][c] = src[rowBase(row) + c*cStride]; row = (b, o, p).
// Block: 64 rows x 256 cols, 256 threads, 8x8 register tile each.
// ---------------------------------------------------------------------------
template <int CIN>
__global__ __launch_bounds__(256) void proj_gemm(
    const float* __restrict__ src, const float* __restrict__ Wm,
    float* __restrict__ outp, int outer, int bStride, int oStride,
    int pStride, int cStride) {
  __shared__ float sA[16][64];
  __shared__ float sW[16][256];
  __shared__ int sRB[64];
  const int tid = threadIdx.x;
  if (tid < 64) {
    int rr = blockIdx.x * 64 + tid;
    int bb = rr / (outer * HW_N);
    int rem = rr - bb * outer * HW_N;
    int o = rem / HW_N;
    int p = rem - o * HW_N;
    sRB[tid] = bb * bStride + o * oStride + p * pStride;
  }
  __syncthreads();
  float accv[8][8];
#pragma unroll
  for (int i = 0; i < 8; i++)
#pragma unroll
    for (int j = 0; j < 8; j++) accv[i][j] = 0.f;
  const int r0 = (tid >> 5) * 8;
  const int c0 = tid & 31;
  for (int k0 = 0; k0 < CIN; k0 += 16) {
    if (k0) __syncthreads();
#pragma unroll
    for (int i = 0; i < 4; i++) {
      int idx = i * 256 + tid;
      int kk = idx >> 6, r = idx & 63;
      sA[kk][r] = src[sRB[r] + (k0 + kk) * cStride];
    }
#pragma unroll
    for (int i = 0; i < 16; i++) sW[i][tid] = Wm[(k0 + i) * E_N + tid];
    __syncthreads();
#pragma unroll 1
    for (int kk = 0; kk < 16; kk++) {
      float4 a0 = *(const float4*)&sA[kk][r0];
      float4 a1 = *(const float4*)&sA[kk][r0 + 4];
      float a[8] = {a0.x, a0.y, a0.z, a0.w, a1.x, a1.y, a1.z, a1.w};
#pragma unroll
      for (int j = 0; j < 8; j++) {
        float wv = sW[kk][c0 + 32 * j];
#pragma unroll
        for (int i = 0; i < 8; i++) accv[i][j] = fmaf(a[i], wv, accv[i][j]);
      }
    }
  }
  const int rowG = blockIdx.x * 64;
#pragma unroll
  for (int i = 0; i < 8; i++)
#pragma unroll
    for (int j = 0; j < 8; j++)
      outp[(rowG + r0 + i) * E_N + c0 + 32 * j] = accv[i][j];
}

// ---------------------------------------------------------------------------
// LayerNorm over E=256, fp32 in -> bf16 out. One wave per row.
// ---------------------------------------------------------------------------
__global__ __launch_bounds__(256) void ln_bf16(
    const float* __restrict__ src, const float* __restrict__ g,
    const float* __restrict__ bb, unsigned short* __restrict__ dst) {
  const int w = threadIdx.x >> 6, lane = threadIdx.x & 63;
  const int row = blockIdx.x * 4 + w;
  const float4 x = *(const float4*)&src[row * E_N + lane * 4];
  float s = x.x + x.y + x.z + x.w;
#pragma unroll
  for (int off = 32; off; off >>= 1) s += __shfl_xor(s, off);
  const float mean = s * (1.f / 256.f);
  float4 d = {x.x - mean, x.y - mean, x.z - mean, x.w - mean};
  float v = d.x * d.x + d.y * d.y + d.z * d.z + d.w * d.w;
#pragma unroll
  for (int off = 32; off; off >>= 1) v += __shfl_xor(v, off);
  const float rstd = rsqrtf(v * (1.f / 256.f) + 1e-5f);
  const float4 gv = *(const float4*)&g[lane * 4];
  const float4 bv = *(const float4*)&bb[lane * 4];
  ushort4 o;
  o.x = f2bf(fmaf(d.x * rstd, gv.x, bv.x));
  o.y = f2bf(fmaf(d.y * rstd, gv.y, bv.y));
  o.z = f2bf(fmaf(d.z * rstd, gv.z, bv.z));
  o.w = f2bf(fmaf(d.w * rstd, gv.w, bv.w));
  *(ushort4*)&dst[row * E_N + lane * 4] = o;
}

// ---------------------------------------------------------------------------
// Flash-style slab cross attention, bf16 MFMA 16x16x32.
// grid 2304 = (pb 9) x (z 32) x (h 4) x (b 2), 256 threads = 4 waves.
// Wave w owns 16 query rows (pixels p0+w*16..+15), all of HD=64.
// ---------------------------------------------------------------------------
__global__ __launch_bounds__(256) void attn_kernel(
    const unsigned short* __restrict__ Qbf, const unsigned short* __restrict__ Kbf,
    const unsigned short* __restrict__ Vbf, const float* __restrict__ topo,
    const float* __restrict__ lamp, const int* __restrict__ D0p,
    const int* __restrict__ slabp, float* __restrict__ O) {
  const int bid = blockIdx.x;
  const int pb = bid % 9;
  const int z = (bid / 9) & 31;
  const int h = (bid / (9 * 32)) & 3;
  const int b = bid / (9 * 32 * 4);
  const int p0 = pb * 64;
  const int tid = threadIdx.x;
  const int w = tid >> 6, lane = tid & 63;
  const int quad = lane >> 4, col = lane & 15;

  const float lam = lamp[0];
  const int D0 = D0p[0], slab = slabp[0];
  // k_index[z] = clip(round(z*(D0-1)/(Dz-1)) // slab, 0, K-1); no .5 ties here
  const float step = (float)(D0 - 1) / (float)(DZ_N - 1);
  int z0 = (int)floorf(fmaf((float)z, step, 0.5f));
  int kk = z0 / slab;
  if (kk > K_N - 1) kk = K_N - 1;
  if (kk < 0) kk = 0;

  __shared__ unsigned short sQ[64][72];      // [q][d], pad 72
  __shared__ unsigned short sK[64][72];      // [m][d]
  __shared__ unsigned short sVt[64][72];     // [d][m] (transposed)
  __shared__ unsigned short sP[4][16][72];   // per-wave P round-trip

  {  // stage Q tile (64 q x 64 d)
    int m = tid >> 2, jj = tid & 3;
    const unsigned short* src =
        &Qbf[((b * DZ_N + z) * HW_N + p0 + m) * E_N + h * 64 + jj * 16];
    *(uint4*)&sQ[m][jj * 16] = *(const uint4*)src;
    *(uint4*)&sQ[m][jj * 16 + 8] = *(const uint4*)(src + 8);
  }
  __syncthreads();
  const bf16x8 aq0 = *(const bf16x8*)&sQ[w * 16 + col][quad * 8];
  const bf16x8 aq1 = *(const bf16x8*)&sQ[w * 16 + col][32 + quad * 8];

  f32x4 oacc[4];
#pragma unroll
  for (int dt = 0; dt < 4; dt++) oacc[dt] = (f32x4){0.f, 0.f, 0.f, 0.f};
  float mrun[4] = {-1e30f, -1e30f, -1e30f, -1e30f};
  float lrun[4] = {0.f, 0.f, 0.f, 0.f};

  for (int ci = 0; ci < 3; ci++) {
    const int c = kk - 1 + ci;
    if (c < 0 || c >= K_N) continue;
    const float bias = (c == kk) ? 0.f : -0.5f;
    for (int pc = 0; pc < 9; pc++) {
      __syncthreads();
      {  // stage K chunk [m][d] and V chunk transposed [d][m]
        int m = tid >> 2, jj = tid & 3;
        const int rowbase = ((b * K_N + c) * HW_N + pc * 64 + m) * E_N + h * 64;
        const unsigned short* ks = &Kbf[rowbase + jj * 16];
        *(uint4*)&sK[m][jj * 16] = *(const uint4*)ks;
        *(uint4*)&sK[m][jj * 16 + 8] = *(const uint4*)(ks + 8);
        const unsigned short* vs = &Vbf[rowbase + jj * 16];
        unsigned short tmp[16];
        *(uint4*)&tmp[0] = *(const uint4*)vs;
        *(uint4*)&tmp[8] = *(const uint4*)(vs + 8);
#pragma unroll
        for (int i = 0; i < 16; i++) sVt[jj * 16 + i][m] = tmp[i];
      }
      __syncthreads();

      // S = Q @ K^T  (4 col tiles of 16 keys)
      f32x4 sv[4];
#pragma unroll
      for (int ct = 0; ct < 4; ct++) {
        f32x4 acc = (f32x4){0.f, 0.f, 0.f, 0.f};
        bf16x8 bk0 = *(const bf16x8*)&sK[ct * 16 + col][quad * 8];
        bf16x8 bk1 = *(const bf16x8*)&sK[ct * 16 + col][32 + quad * 8];
        acc = __builtin_amdgcn_mfma_f32_16x16x32_bf16(aq0, bk0, acc, 0, 0, 0);
        acc = __builtin_amdgcn_mfma_f32_16x16x32_bf16(aq1, bk1, acc, 0, 0, 0);
#pragma unroll
        for (int r = 0; r < 4; r++) sv[ct][r] = fmaf(acc[r], 0.125f, bias);
      }
      // diag: key pixel == query pixel (only when pixel chunks align)
      if (pc == pb) {
        float tv = 0.f;
        if ((col >> 2) == quad)
          tv = lam * topo[(b * K_N + c) * HW_N + p0 + w * 16 + col];
#pragma unroll
        for (int ct = 0; ct < 4; ct++)
#pragma unroll
          for (int r = 0; r < 4; r++)
            sv[ct][r] += (ct == w && (col & 3) == r) ? tv : 0.f;
      }
      // online softmax per row (row r lives on the 16 lanes of this quad)
#pragma unroll
      for (int r = 0; r < 4; r++) {
        float mx = fmaxf(fmaxf(sv[0][r], sv[1][r]), fmaxf(sv[2][r], sv[3][r]));
        mx = fmaxf(mx, __shfl_xor(mx, 1));
        mx = fmaxf(mx, __shfl_xor(mx, 2));
        mx = fmaxf(mx, __shfl_xor(mx, 4));
        mx = fmaxf(mx, __shfl_xor(mx, 8));
        const float mnew = fmaxf(mrun[r], mx);
        const float alpha = __expf(mrun[r] - mnew);
        mrun[r] = mnew;
        float rs = 0.f;
#pragma unroll
        for (int ct = 0; ct < 4; ct++) {
          float e = __expf(sv[ct][r] - mnew);
          sv[ct][r] = e;
          rs += e;
        }
        rs += __shfl_xor(rs, 1);
        rs += __shfl_xor(rs, 2);
        rs += __shfl_xor(rs, 4);
        rs += __shfl_xor(rs, 8);
        lrun[r] = lrun[r] * alpha + rs;
#pragma unroll
        for (int dt = 0; dt < 4; dt++) oacc[dt][r] *= alpha;
      }
      // P: C-layout -> LDS -> A-layout (bf16)
#pragma unroll
      for (int ct = 0; ct < 4; ct++)
#pragma unroll
        for (int r = 0; r < 4; r++)
          sP[w][quad * 4 + r][ct * 16 + col] = f2bf(sv[ct][r]);
      const bf16x8 ap0 = *(const bf16x8*)&sP[w][col][quad * 8];
      const bf16x8 ap1 = *(const bf16x8*)&sP[w][col][32 + quad * 8];
      // O += P @ V
#pragma unroll
      for (int dt = 0; dt < 4; dt++) {
        bf16x8 bv0 = *(const bf16x8*)&sVt[dt * 16 + col][quad * 8];
        bf16x8 bv1 = *(const bf16x8*)&sVt[dt * 16 + col][32 + quad * 8];
        oacc[dt] = __builtin_amdgcn_mfma_f32_16x16x32_bf16(ap0, bv0, oacc[dt], 0, 0, 0);
        oacc[dt] = __builtin_amdgcn_mfma_f32_16x16x32_bf16(ap1, bv1, oacc[dt], 0, 0, 0);
      }
    }
  }
  // epilogue: O[(b,z,p)][h*64 + d] = oacc / l
#pragma unroll
  for (int r = 0; r < 4; r++) {
    const float invl = 1.f / lrun[r];
    const int row = (b * DZ_N + z) * HW_N + p0 + w * 16 + quad * 4 + r;
#pragma unroll
    for (int dt = 0; dt < 4; dt++)
      O[row * E_N + h * 64 + dt * 16 + col] = oacc[dt][r] * invl;
  }
}

// ---------------------------------------------------------------------------
// Output projection + residual: out[b,c,z,p] = F3[b,c,z,p] + O[(b,z,p)][:] @ Wp[:,c]
// Block: 64 rows x 128 cols; LDS transpose for coalesced (c,p) writes.
// ---------------------------------------------------------------------------
__global__ __launch_bounds__(256) void out_proj(
    const float* __restrict__ O, const float* __restrict__ Wp,
    const float* __restrict__ F3, float* __restrict__ outp) {
  __shared__ float sA[16][68];   // [k][row], pad 68
  __shared__ float sW[16][128];
  __shared__ float sOut[64][129];
  const int tid = threadIdx.x;
  const int rowG = blockIdx.x * 64;
  float accv[8][4];
#pragma unroll
  for (int i = 0; i < 8; i++)
#pragma unroll
    for (int j = 0; j < 4; j++) accv[i][j] = 0.f;
  const int r0 = (tid >> 5) * 8;
  const int c0 = tid & 31;
  for (int k0 = 0; k0 < 256; k0 += 16) {
    if (k0) __syncthreads();
#pragma unroll
    for (int i = 0; i < 4; i++) {
      int idx = i * 256 + tid;
      int r = idx >> 4, kk = idx & 15;   // lanes along k (contiguous in O)
      sA[kk][r] = O[(rowG + r) * E_N + k0 + kk];
    }
#pragma unroll
    for (int i = 0; i < 8; i++) {
      int idx = i * 256 + tid;
      int kk = idx >> 7, ccc = idx & 127;
      sW[kk][ccc] = Wp[(k0 + kk) * C3_N + ccc];
    }
    __syncthreads();
#pragma unroll 1
    for (int kk = 0; kk < 16; kk++) {
      float4 a0 = *(const float4*)&sA[kk][r0];
      float4 a1 = *(const float4*)&sA[kk][r0 + 4];
      float a[8] = {a0.x, a0.y, a0.z, a0.w, a1.x, a1.y, a1.z, a1.w};
#pragma unroll
      for (int j = 0; j < 4; j++) {
        float wv = sW[kk][c0 + 32 * j];
#pragma unroll
        for (int i = 0; i < 8; i++) accv[i][j] = fmaf(a[i], wv, accv[i][j]);
      }
    }
  }
  __syncthreads();
#pragma unroll
  for (int i = 0; i < 8; i++)
#pragma unroll
    for (int j = 0; j < 4; j++) sOut[r0 + i][c0 + 32 * j] = accv[i][j];
  __syncthreads();
  const int b = rowG / (DZ_N * HW_N);
  const int rem = rowG - b * DZ_N * HW_N;
  const int z = rem / HW_N;
  const int pp0 = rem - z * HW_N;
  const int pl = tid & 63, cg = tid >> 6;
  for (int cch = cg * 32; cch < cg * 32 + 32; cch++) {
    const int gidx = ((b * C3_N + cch) * DZ_N + z) * HW_N + pp0 + pl;
    outp[gidx] = F3[gidx] + sOut[pl][cch];
  }
}

// ---------------------------------------------------------------------------
extern "C" void kernel_launch(void* const* d_in, const int* in_sizes, int n_in,
                              void* d_out, int out_size, void* d_ws, size_t ws_size,
                              hipStream_t stream) {
  (void)in_sizes; (void)n_in; (void)out_size; (void)ws_size;
  const float* F3      = (const float*)d_in[0];
  const float* F2      = (const float*)d_in[1];
  const float* Wq      = (const float*)d_in[2];
  const float* Wk      = (const float*)d_in[3];
  const float* Wv      = (const float*)d_in[4];
  const float* Wp      = (const float*)d_in[5];
  const float* ln_q_g  = (const float*)d_in[6];
  const float* ln_q_b  = (const float*)d_in[7];
  const float* ln_kv_g = (const float*)d_in[8];
  const float* ln_kv_b = (const float*)d_in[9];
  const float* conv1_w = (const float*)d_in[10];
  const float* bn_g    = (const float*)d_in[11];
  const float* bn_b    = (const float*)d_in[12];
  const float* conv2_w = (const float*)d_in[13];
  const float* conv2_b = (const float*)d_in[14];
  const float* lam     = (const float*)d_in[15];
  const int*   D0      = (const int*)d_in[16];
  const int*   slab    = (const int*)d_in[17];
  float* out = (float*)d_out;

  // workspace layout (~85 MB, 256B-aligned chunks)
  char* ws = (char*)d_ws;
  size_t off = 0;
  auto alloc = [&](size_t bytes) {
    void* p = ws + off;
    off += (bytes + 255) & ~(size_t)255;
    return p;
  };
  const int QROWS = B_N * DZ_N * HW_N;   // 36864
  const int KVROWS = B_N * K_N * HW_N;   // 9216
  float* Qraw = (float*)alloc((size_t)QROWS * E_N * 4);   // reused as O after LN-Q
  float* Kraw = (float*)alloc((size_t)KVROWS * E_N * 4);  // reused: Hp lives here first
  float* Vraw = (float*)alloc((size_t)KVROWS * E_N * 4);
  unsigned short* Qbf = (unsigned short*)alloc((size_t)QROWS * E_N * 2);
  unsigned short* Kbf = (unsigned short*)alloc((size_t)KVROWS * E_N * 2);
  unsigned short* Vbf = (unsigned short*)alloc((size_t)KVROWS * E_N * 2);
  float* topo = (float*)alloc((size_t)B_N * K_N * HW_N * 4);
  float* Hp = Kraw;   // 4*16*64*576*4 B == KVROWS*E_N*4 B; dead before gemm-K runs
  float* O  = Qraw;   // Qraw dead after ln_bf16(Q)

  // 1) topo branch (must finish before attention; Hp freed before gemm-K)
  topo_conv1<<<256, 384, 0, stream>>>(F2, conv1_w, Hp);
  topo_final<<<16, 576, 0, stream>>>(Hp, bn_g, bn_b, conv2_w, conv2_b, topo);
  // 2) projections (fp32)
  proj_gemm<128><<<QROWS / 64, 256, 0, stream>>>(
      F3, Wq, Qraw, DZ_N, C3_N * DZ_N * HW_N, HW_N, 1, DZ_N * HW_N);
  proj_gemm<96><<<KVROWS / 64, 256, 0, stream>>>(
      F2, Wk, Kraw, K_N, C2_N * HW_N * K_N, 1, K_N, HW_N * K_N);
  proj_gemm<96><<<KVROWS / 64, 256, 0, stream>>>(
      F2, Wv, Vraw, K_N, C2_N * HW_N * K_N, 1, K_N, HW_N * K_N);
  // 3) layernorm -> bf16
  ln_bf16<<<QROWS / 4, 256, 0, stream>>>(Qraw, ln_q_g, ln_q_b, Qbf);
  ln_bf16<<<KVROWS / 4, 256, 0, stream>>>(Kraw, ln_kv_g, ln_kv_b, Kbf);
  ln_bf16<<<KVROWS / 4, 256, 0, stream>>>(Vraw, ln_kv_g, ln_kv_b, Vbf);
  // 4) attention (writes O = Qraw region)
  attn_kernel<<<9 * 32 * 4 * 2, 256, 0, stream>>>(
      Qbf, Kbf, Vbf, topo, lam, D0, slab, O);
  // 5) output projection + residual
  out_proj<<<QROWS / 64, 256, 0, stream>>>(O, Wp, F3, out);
}

// Round 2
// 436.981 us; speedup vs baseline: 1.2767x; 1.2767x over previous
//
#include <hip/hip_runtime.h>

typedef float f32x4 __attribute__((ext_vector_type(4)));
typedef __bf16 bf16x8 __attribute__((ext_vector_type(8)));
typedef unsigned short ushort_t;

#define DEV_INLINE __device__ __forceinline__

constexpr int B_N  = 2;
constexpr int C3_N = 128;
constexpr int C2_N = 96;
constexpr int DZ_N = 32;
constexpr int H_N  = 24;
constexpr int W_N  = 24;
constexpr int K_N  = 8;
constexpr int E_N  = 256;
constexpr int HW_N = 576;

DEV_INLINE unsigned short f2bf(float x) {
  union { float f; unsigned u; } v; v.f = x;
  unsigned r = v.u + 0x7FFFu + ((v.u >> 16) & 1u);
  return (unsigned short)(r >> 16);
}

// ---------------------------------------------------------------------------
// Topo kernel A: partial 3x3 conv (C2->64), split over 4 c-chunks of 24.
// ---------------------------------------------------------------------------
__global__ __launch_bounds__(384) void topo_conv1(
    const float* __restrict__ F2, const float* __restrict__ W1,
    float* __restrict__ Hp) {
  const int bid = blockIdx.x;
  const int cc = bid & 3;
  const int tg = (bid >> 2) & 3;
  const int bk = bid >> 4;           // 0..15 = b*8 + k
  const int b = bk >> 3, k = bk & 7;
  const int tid = threadIdx.x;
  const int y = tid >> 4;            // 0..23
  const int tq = tid & 15;           // 0..15

  __shared__ float simg[8][26][28];
  __shared__ float sw[16 * 97];

  float acc[24];
#pragma unroll
  for (int i = 0; i < 24; i++) acc[i] = 0.f;

  float* simgf = &simg[0][0][0];
  for (int i = tid; i < 8 * 26 * 28; i += 384) simgf[i] = 0.f;
  __syncthreads();

  for (int ch = 0; ch < 3; ch++) {
    if (ch) __syncthreads();
    const int c0 = cc * 24 + ch * 8;
    for (int i = tid; i < 8 * 24 * 24; i += 384) {
      int c = i / 576, p = i - c * 576;
      int yy = p / 24, xx = p - yy * 24;
      simg[c][yy + 1][xx + 1] =
          F2[(((b * C2_N + c0 + c) * H_N + yy) * W_N + xx) * K_N + k];
    }
    for (int i = tid; i < 16 * 72; i += 384) {
      int t2 = i / 72, rest = i - t2 * 72;
      int c = rest / 9, q = rest - c * 9;
      sw[t2 * 97 + c * 12 + q] =
          W1[(tg * 16 + t2) * (C2_N * 9) + (c0 + c) * 9 + q];
    }
    __syncthreads();
#pragma unroll 1
    for (int c = 0; c < 8; c++) {
      float w[9];
#pragma unroll
      for (int q = 0; q < 9; q++) w[q] = sw[tq * 97 + c * 12 + q];
#pragma unroll
      for (int dy = 0; dy < 3; dy++) {
        float r[26];
#pragma unroll
        for (int xx = 0; xx < 26; xx++) r[xx] = simg[c][y + dy][xx];
#pragma unroll
        for (int dx = 0; dx < 3; dx++) {
          float wv = w[dy * 3 + dx];
#pragma unroll
          for (int xx = 0; xx < 24; xx++)
            acc[xx] = fmaf(wv, r[xx + dx], acc[xx]);
        }
      }
    }
  }
  const int t = tg * 16 + tq;
  float* dst = &Hp[((cc * 16 + bk) * 64 + t) * HW_N + y * 24];
#pragma unroll
  for (int xx = 0; xx < 24; xx++) dst[xx] = acc[xx];
}

// ---------------------------------------------------------------------------
// Topo kernel B: sum partials, bn+relu, 1x1 conv, neighbor sum.
// ---------------------------------------------------------------------------
__global__ __launch_bounds__(576) void topo_final(
    const float* __restrict__ Hp, const float* __restrict__ bn_g,
    const float* __restrict__ bn_b, const float* __restrict__ W2,
    const float* __restrict__ b2, float* __restrict__ topo) {
  const int bk = blockIdx.x;
  const int p = threadIdx.x;
  __shared__ float pp[26][28];
  float* ppf = &pp[0][0];
  for (int i = p; i < 26 * 28; i += 576) ppf[i] = 0.f;

  const float inv = rsqrtf(1.0f + 1e-5f);
  float acc = b2[0];
  for (int t = 0; t < 64; t++) {
    float v = 0.f;
#pragma unroll
    for (int c4 = 0; c4 < 4; c4++)
      v += Hp[((c4 * 16 + bk) * 64 + t) * HW_N + p];
    float hcv = fmaxf(fmaf(bn_g[t] * inv, v, bn_b[t]), 0.f);
    acc = fmaf(W2[t], hcv, acc);
  }
  __syncthreads();
  pp[p / 24 + 1][p % 24 + 1] = acc;
  __syncthreads();
  const int yy = p / 24 + 1, xx = p % 24 + 1;
  float s = pp[yy-1][xx-1] + pp[yy-1][xx] + pp[yy-1][xx+1]
          + pp[yy][xx-1]                  + pp[yy][xx+1]
          + pp[yy+1][xx-1] + pp[yy+1][xx] + pp[yy+1][xx+1];
  topo[bk * HW_N + p] = acc + 0.5f * s;
}

// ---------------------------------------------------------------------------
// Projection GEMM (fp32 vector), unchanged from R1.
// ---------------------------------------------------------------------------
template <int CIN>
__global__ __launch_bounds__(256) void proj_gemm(
    const float* __restrict__ src, const float* __restrict__ Wm,
    float* __restrict__ outp, int outer, int bStride, int oStride,
    int pStride, int cStride) {
  __shared__ float sA[16][64];
  __shared__ float sW[16][256];
  __shared__ int sRB[64];
  const int tid = threadIdx.x;
  if (tid < 64) {
    int rr = blockIdx.x * 64 + tid;
    int bb = rr / (outer * HW_N);
    int rem = rr - bb * outer * HW_N;
    int o = rem / HW_N;
    int p = rem - o * HW_N;
    sRB[tid] = bb * bStride + o * oStride + p * pStride;
  }
  __syncthreads();
  float accv[8][8];
#pragma unroll
  for (int i = 0; i < 8; i++)
#pragma unroll
    for (int j = 0; j < 8; j++) accv[i][j] = 0.f;
  const int r0 = (tid >> 5) * 8;
  const int c0 = tid & 31;
  for (int k0 = 0; k0 < CIN; k0 += 16) {
    if (k0) __syncthreads();
#pragma unroll
    for (int i = 0; i < 4; i++) {
      int idx = i * 256 + tid;
      int kk = idx >> 6, r = idx & 63;
      sA[kk][r] = src[sRB[r] + (k0 + kk) * cStride];
    }
#pragma unroll
    for (int i = 0; i < 16; i++) sW[i][tid] = Wm[(k0 + i) * E_N + tid];
    __syncthreads();
#pragma unroll 1
    for (int kk = 0; kk < 16; kk++) {
      float4 a0 = *(const float4*)&sA[kk][r0];
      float4 a1 = *(const float4*)&sA[kk][r0 + 4];
      float a[8] = {a0.x, a0.y, a0.z, a0.w, a1.x, a1.y, a1.z, a1.w};
#pragma unroll
      for (int j = 0; j < 8; j++) {
        float wv = sW[kk][c0 + 32 * j];
#pragma unroll
        for (int i = 0; i < 8; i++) accv[i][j] = fmaf(a[i], wv, accv[i][j]);
      }
    }
  }
  const int rowG = blockIdx.x * 64;
#pragma unroll
  for (int i = 0; i < 8; i++)
#pragma unroll
    for (int j = 0; j < 8; j++)
      outp[(rowG + r0 + i) * E_N + c0 + 32 * j] = accv[i][j];
}

// ---------------------------------------------------------------------------
// LayerNorm over E=256, fp32 in -> bf16 out. One wave per row.
// ---------------------------------------------------------------------------
__global__ __launch_bounds__(256) void ln_bf16(
    const float* __restrict__ src, const float* __restrict__ g,
    const float* __restrict__ bb, ushort_t* __restrict__ dst) {
  const int w = threadIdx.x >> 6, lane = threadIdx.x & 63;
  const int row = blockIdx.x * 4 + w;
  const float4 x = *(const float4*)&src[row * E_N + lane * 4];
  float s = x.x + x.y + x.z + x.w;
#pragma unroll
  for (int off = 32; off; off >>= 1) s += __shfl_xor(s, off);
  const float mean = s * (1.f / 256.f);
  float4 d = {x.x - mean, x.y - mean, x.z - mean, x.w - mean};
  float v = d.x * d.x + d.y * d.y + d.z * d.z + d.w * d.w;
#pragma unroll
  for (int off = 32; off; off >>= 1) v += __shfl_xor(v, off);
  const float rstd = rsqrtf(v * (1.f / 256.f) + 1e-5f);
  const float4 gv = *(const float4*)&g[lane * 4];
  const float4 bv = *(const float4*)&bb[lane * 4];
  ushort4 o;
  o.x = f2bf(fmaf(d.x * rstd, gv.x, bv.x));
  o.y = f2bf(fmaf(d.y * rstd, gv.y, bv.y));
  o.z = f2bf(fmaf(d.z * rstd, gv.z, bv.z));
  o.w = f2bf(fmaf(d.w * rstd, gv.w, bv.w));
  *(ushort4*)&dst[row * E_N + lane * 4] = o;
}

// ---------------------------------------------------------------------------
// pack_k: Kbf rows -> per-(b,slab,head,chunk) 8KB blocks [m][d], 16B groups
// XOR-swizzled by (m&7) so attn B-frag reads are bank-uniform.
// grid 144 = (b*8+k)*9+pc, 256 thr: thread = (m 0..63, h 0..3).
// ---------------------------------------------------------------------------
__global__ __launch_bounds__(256) void pack_k(
    const ushort_t* __restrict__ Kbf, ushort_t* __restrict__ Kpk) {
  const int bid = blockIdx.x;
  const int pc = bid % 9;
  const int bk = bid / 9;
  const int tid = threadIdx.x;
  const int m = tid >> 2, h = tid & 3;
  const int row = bk * HW_N + pc * 64 + m;
  const uint4* src = (const uint4*)&Kbf[row * E_N + h * 64];
  uint4 v[8];
#pragma unroll
  for (int g = 0; g < 8; g++) v[g] = src[g];
  const int chunk = (bk * 4 + h) * 9 + pc;
  uint4* dst = (uint4*)&Kpk[chunk * 4096 + m * 64];
  const int sw = m & 7;
#pragma unroll
  for (int g = 0; g < 8; g++) dst[g ^ sw] = v[g];
}

// ---------------------------------------------------------------------------
// pack_vt: Vbf rows -> transposed per-(b,slab,head,chunk) 8KB blocks [d][m],
// 16B groups XOR-swizzled by (d&7). LDS tile transpose.
// ---------------------------------------------------------------------------
__global__ __launch_bounds__(256) void pack_vt(
    const ushort_t* __restrict__ Vbf, ushort_t* __restrict__ Vtp) {
  const int bid = blockIdx.x;
  const int pc = bid % 9;
  const int bk = bid / 9;
  const int tid = threadIdx.x;
  __shared__ ushort_t sT[64][264];   // pitch 264 shorts (132 dw) vs conflicts
  {
    const int m = tid >> 2, jj = tid & 3;
    const int row = bk * HW_N + pc * 64 + m;
    const uint4* src = (const uint4*)&Vbf[row * E_N + jj * 64];
    uint4* d = (uint4*)&sT[m][jj * 64];
#pragma unroll
    for (int g = 0; g < 8; g++) d[g] = src[g];
  }
  __syncthreads();
  const int hh = tid >> 6, d = tid & 63;
  __attribute__((aligned(16))) ushort_t tmp[64];
#pragma unroll
  for (int m = 0; m < 64; m++) tmp[m] = sT[m][hh * 64 + d];
  const int chunk = (bk * 4 + hh) * 9 + pc;
  uint4* dst = (uint4*)&Vtp[chunk * 4096 + d * 64];
  const int sw = d & 7;
#pragma unroll
  for (int g = 0; g < 8; g++) dst[g ^ sw] = ((const uint4*)tmp)[g];
}

// ---------------------------------------------------------------------------
// Flash-style slab cross attention v2.
// grid 1152 = (pb 9) x (zp 16) x (h 4) x (b 2), 256 thr = 4 waves.
// Wave w: z = 2*zp + (w>>1), q-rows [p0 + (w&1)*32, +32) as two 16-row tiles.
// Fixed-max softmax in exp2 domain; K/Vt staged from swizzled packed chunks.
// ---------------------------------------------------------------------------
__global__ __launch_bounds__(256) void attn_kernel(
    const ushort_t* __restrict__ Qbf, const ushort_t* __restrict__ Kpk,
    const ushort_t* __restrict__ Vtp, const float* __restrict__ topo,
    const float* __restrict__ lamp, const int* __restrict__ D0p,
    const int* __restrict__ slabp, float* __restrict__ O) {
  const int bid = blockIdx.x;
  const int pb = bid % 9;
  const int zp = (bid / 9) & 15;
  const int h  = (bid / 144) & 3;
  const int b  = bid / 576;
  const int p0 = pb * 64;
  const int tid = threadIdx.x;
  const int w = tid >> 6, lane = tid & 63;
  const int quad = lane >> 4, col = lane & 15;
  const int z = zp * 2 + (w >> 1);
  const int qh = w & 1;

  const float LOG2E = 1.44269504f;
  const float lam2 = lamp[0] * LOG2E;
  const float S2 = 0.125f * LOG2E;          // qk scale folded into exp2 domain
  const int D0 = D0p[0], slab = slabp[0];
  const float step = (float)(D0 - 1) / (float)(DZ_N - 1);

  int kkw, kka, kkb;
  {
    int z0 = (int)floorf(fmaf((float)z, step, 0.5f));
    int kv = z0 / slab;
    kkw = kv < 0 ? 0 : (kv > K_N - 1 ? K_N - 1 : kv);
    int za = zp * 2, zb = zp * 2 + 1;
    int z0a = (int)floorf(fmaf((float)za, step, 0.5f));
    int z0b = (int)floorf(fmaf((float)zb, step, 0.5f));
    int ka = z0a / slab; ka = ka < 0 ? 0 : (ka > K_N - 1 ? K_N - 1 : ka);
    int kb = z0b / slab; kb = kb < 0 ? 0 : (kb > K_N - 1 ? K_N - 1 : kb);
    kka = ka < kb ? ka : kb;
    kkb = ka < kb ? kb : ka;
  }
  const int c_lo = (kka - 1) < 0 ? 0 : (kka - 1);
  const int c_hi = (kkb + 1) > (K_N - 1) ? (K_N - 1) : (kkb + 1);

  __shared__ ushort_t sK[64 * 64];     // packed/swizzled, byte-copy of chunk
  __shared__ ushort_t sVt[64 * 64];
  __shared__ ushort_t sP[4][32][68];   // pitch 68 -> conflict-free writes/reads

  // Q A-fragments direct from global (once per block)
  bf16x8 aq[2][2];
  const int qrow0 = (b * DZ_N + z) * HW_N + p0 + qh * 32;
#pragma unroll
  for (int t = 0; t < 2; t++) {
    const ushort_t* qp = &Qbf[(qrow0 + t * 16 + col) * E_N + h * 64 + quad * 8];
    aq[t][0] = *(const bf16x8*)qp;
    aq[t][1] = *(const bf16x8*)(qp + 32);
  }

  f32x4 oacc[2][4];
#pragma unroll
  for (int t = 0; t < 2; t++)
#pragma unroll
    for (int dt = 0; dt < 4; dt++) oacc[t][dt] = (f32x4){0.f, 0.f, 0.f, 0.f};
  float lsum[2][4] = {{0.f,0.f,0.f,0.f},{0.f,0.f,0.f,0.f}};

  for (int c = c_lo; c <= c_hi; c++) {
    const bool act = (c >= kkw - 1) && (c <= kkw + 1);
    const float biasE2 = ((c == kkw) ? -20.0f : -20.5f) * LOG2E;  // fixed max 20
    const int cb = (((b * K_N + c) * 4 + h) * 9) * 4096;
    for (int pc = 0; pc < 9; pc++) {
      __syncthreads();
      {  // stage 8KB K + 8KB Vt (byte-identical copy; swizzle baked in global)
        const uint4* gk = (const uint4*)(Kpk + cb + pc * 4096);
        const uint4* gv = (const uint4*)(Vtp + cb + pc * 4096);
        uint4* dk = (uint4*)sK;
        uint4* dv = (uint4*)sVt;
        dk[tid] = gk[tid]; dk[tid + 256] = gk[tid + 256];
        dv[tid] = gv[tid]; dv[tid + 256] = gv[tid + 256];
      }
      __syncthreads();
      if (!act) continue;

      // ---- S = Q K^T (bank-uniform swizzled B reads) ----
      f32x4 qk[2][4];
#pragma unroll
      for (int ct = 0; ct < 4; ct++) {
        const int kr = ct * 16 + col;
        const int s7 = kr & 7;
        bf16x8 bk0 = *(const bf16x8*)&sK[kr * 64 + ((quad ^ s7) * 8)];
        bf16x8 bk1 = *(const bf16x8*)&sK[kr * 64 + (((quad + 4) ^ s7) * 8)];
#pragma unroll
        for (int t = 0; t < 2; t++) {
          f32x4 acc = (f32x4){0.f, 0.f, 0.f, 0.f};
          acc = __builtin_amdgcn_mfma_f32_16x16x32_bf16(aq[t][0], bk0, acc, 0, 0, 0);
          acc = __builtin_amdgcn_mfma_f32_16x16x32_bf16(aq[t][1], bk1, acc, 0, 0, 0);
          qk[t][ct] = acc;
        }
      }

      // ---- fixed-max softmax (exp2 domain), P -> sP (truncate to bf16) ----
#pragma unroll
      for (int t = 0; t < 2; t++) {
        const int ctt = qh * 2 + t;   // diag key-tile for this q-tile
        float tv2 = 0.f;
        if (pc == pb && (col >> 2) == quad)
          tv2 = lam2 * topo[(b * K_N + c) * HW_N + p0 + qh * 32 + t * 16 + col];
#pragma unroll
        for (int ct = 0; ct < 4; ct++) {
#pragma unroll
          for (int r = 0; r < 4; r++) {
            float x = fmaf(qk[t][ct][r], S2, biasE2);
            if (pc == pb && ct == ctt)
              x += ((col & 3) == r) ? tv2 : 0.f;
            float e = __builtin_amdgcn_exp2f(x);
            lsum[t][r] += e;
            sP[w][t * 16 + quad * 4 + r][ct * 16 + col] =
                (ushort_t)(__float_as_uint(e) >> 16);
          }
        }
      }

      // ---- O += P V (bv shared across both q-tiles) ----
      bf16x8 ap[2][2];
#pragma unroll
      for (int t = 0; t < 2; t++) {
        ap[t][0] = *(const bf16x8*)&sP[w][t * 16 + col][quad * 8];
        ap[t][1] = *(const bf16x8*)&sP[w][t * 16 + col][32 + quad * 8];
      }
#pragma unroll
      for (int dt = 0; dt < 4; dt++) {
        const int dr = dt * 16 + col;
        const int s7 = dr & 7;
        bf16x8 bv0 = *(const bf16x8*)&sVt[dr * 64 + ((quad ^ s7) * 8)];
        bf16x8 bv1 = *(const bf16x8*)&sVt[dr * 64 + (((quad + 4) ^ s7) * 8)];
#pragma unroll
        for (int t = 0; t < 2; t++) {
          oacc[t][dt] = __builtin_amdgcn_mfma_f32_16x16x32_bf16(ap[t][0], bv0, oacc[t][dt], 0, 0, 0);
          oacc[t][dt] = __builtin_amdgcn_mfma_f32_16x16x32_bf16(ap[t][1], bv1, oacc[t][dt], 0, 0, 0);
        }
      }
    }
  }

  // epilogue: l reduce over the quad's 16 lanes, O = oacc / l
#pragma unroll
  for (int t = 0; t < 2; t++)
#pragma unroll
    for (int r = 0; r < 4; r++) {
      float l = lsum[t][r];
      l += __shfl_xor(l, 1); l += __shfl_xor(l, 2);
      l += __shfl_xor(l, 4); l += __shfl_xor(l, 8);
      const float invl = 1.f / l;
      const int row = qrow0 + t * 16 + quad * 4 + r;
#pragma unroll
      for (int dt = 0; dt < 4; dt++)
        O[row * E_N + h * 64 + dt * 16 + col] = oacc[t][dt][r] * invl;
    }
}

// ---------------------------------------------------------------------------
// Output projection + residual (unchanged from R1).
// ---------------------------------------------------------------------------
__global__ __launch_bounds__(256) void out_proj(
    const float* __restrict__ O, const float* __restrict__ Wp,
    const float* __restrict__ F3, float* __restrict__ outp) {
  __shared__ float sA[16][68];
  __shared__ float sW[16][128];
  __shared__ float sOut[64][129];
  const int tid = threadIdx.x;
  const int rowG = blockIdx.x * 64;
  float accv[8][4];
#pragma unroll
  for (int i = 0; i < 8; i++)
#pragma unroll
    for (int j = 0; j < 4; j++) accv[i][j] = 0.f;
  const int r0 = (tid >> 5) * 8;
  const int c0 = tid & 31;
  for (int k0 = 0; k0 < 256; k0 += 16) {
    if (k0) __syncthreads();
#pragma unroll
    for (int i = 0; i < 4; i++) {
      int idx = i * 256 + tid;
      int r = idx >> 4, kk = idx & 15;
      sA[kk][r] = O[(rowG + r) * E_N + k0 + kk];
    }
#pragma unroll
    for (int i = 0; i < 8; i++) {
      int idx = i * 256 + tid;
      int kk = idx >> 7, ccc = idx & 127;
      sW[kk][ccc] = Wp[(k0 + kk) * C3_N + ccc];
    }
    __syncthreads();
#pragma unroll 1
    for (int kk = 0; kk < 16; kk++) {
      float4 a0 = *(const float4*)&sA[kk][r0];
      float4 a1 = *(const float4*)&sA[kk][r0 + 4];
      float a[8] = {a0.x, a0.y, a0.z, a0.w, a1.x, a1.y, a1.z, a1.w};
#pragma unroll
      for (int j = 0; j < 4; j++) {
        float wv = sW[kk][c0 + 32 * j];
#pragma unroll
        for (int i = 0; i < 8; i++) accv[i][j] = fmaf(a[i], wv, accv[i][j]);
      }
    }
  }
  __syncthreads();
#pragma unroll
  for (int i = 0; i < 8; i++)
#pragma unroll
    for (int j = 0; j < 4; j++) sOut[r0 + i][c0 + 32 * j] = accv[i][j];
  __syncthreads();
  const int b = rowG / (DZ_N * HW_N);
  const int rem = rowG - b * DZ_N * HW_N;
  const int z = rem / HW_N;
  const int pp0 = rem - z * HW_N;
  const int pl = tid & 63, cg = tid >> 6;
  for (int cch = cg * 32; cch < cg * 32 + 32; cch++) {
    const int gidx = ((b * C3_N + cch) * DZ_N + z) * HW_N + pp0 + pl;
    outp[gidx] = F3[gidx] + sOut[pl][cch];
  }
}

// ---------------------------------------------------------------------------
extern "C" void kernel_launch(void* const* d_in, const int* in_sizes, int n_in,
                              void* d_out, int out_size, void* d_ws, size_t ws_size,
                              hipStream_t stream) {
  (void)in_sizes; (void)n_in; (void)out_size; (void)ws_size;
  const float* F3      = (const float*)d_in[0];
  const float* F2      = (const float*)d_in[1];
  const float* Wq      = (const float*)d_in[2];
  const float* Wk      = (const float*)d_in[3];
  const float* Wv      = (const float*)d_in[4];
  const float* Wp      = (const float*)d_in[5];
  const float* ln_q_g  = (const float*)d_in[6];
  const float* ln_q_b  = (const float*)d_in[7];
  const float* ln_kv_g = (const float*)d_in[8];
  const float* ln_kv_b = (const float*)d_in[9];
  const float* conv1_w = (const float*)d_in[10];
  const float* bn_g    = (const float*)d_in[11];
  const float* bn_b    = (const float*)d_in[12];
  const float* conv2_w = (const float*)d_in[13];
  const float* conv2_b = (const float*)d_in[14];
  const float* lam     = (const float*)d_in[15];
  const int*   D0      = (const int*)d_in[16];
  const int*   slab    = (const int*)d_in[17];
  float* out = (float*)d_out;

  char* ws = (char*)d_ws;
  size_t off = 0;
  auto alloc = [&](size_t bytes) {
    void* p = ws + off;
    off += (bytes + 255) & ~(size_t)255;
    return p;
  };
  const int QROWS = B_N * DZ_N * HW_N;   // 36864
  const int KVROWS = B_N * K_N * HW_N;   // 9216
  float* Qraw = (float*)alloc((size_t)QROWS * E_N * 4);   // -> reused as O
  float* Kraw = (float*)alloc((size_t)KVROWS * E_N * 4);  // Hp first, Kpk later
  float* Vraw = (float*)alloc((size_t)KVROWS * E_N * 4);  // Vtp later
  ushort_t* Qbf = (ushort_t*)alloc((size_t)QROWS * E_N * 2);
  ushort_t* Kbf = (ushort_t*)alloc((size_t)KVROWS * E_N * 2);
  ushort_t* Vbf = (ushort_t*)alloc((size_t)KVROWS * E_N * 2);
  float* topo = (float*)alloc((size_t)B_N * K_N * HW_N * 4);
  float* Hp = Kraw;                    // dead before proj_gemm<96> K runs
  ushort_t* Kpk = (ushort_t*)Kraw;     // Kraw dead after ln_bf16(K)
  ushort_t* Vtp = (ushort_t*)Vraw;     // Vraw dead after ln_bf16(V)
  float* O  = Qraw;                    // Qraw dead after ln_bf16(Q)

  // 1) topo branch
  topo_conv1<<<256, 384, 0, stream>>>(F2, conv1_w, Hp);
  topo_final<<<16, 576, 0, stream>>>(Hp, bn_g, bn_b, conv2_w, conv2_b, topo);
  // 2) projections (fp32)
  proj_gemm<128><<<QROWS / 64, 256, 0, stream>>>(
      F3, Wq, Qraw, DZ_N, C3_N * DZ_N * HW_N, HW_N, 1, DZ_N * HW_N);
  proj_gemm<96><<<KVROWS / 64, 256, 0, stream>>>(
      F2, Wk, Kraw, K_N, C2_N * HW_N * K_N, 1, K_N, HW_N * K_N);
  proj_gemm<96><<<KVROWS / 64, 256, 0, stream>>>(
      F2, Wv, Vraw, K_N, C2_N * HW_N * K_N, 1, K_N, HW_N * K_N);
  // 3) layernorm -> bf16
  ln_bf16<<<QROWS / 4, 256, 0, stream>>>(Qraw, ln_q_g, ln_q_b, Qbf);
  ln_bf16<<<KVROWS / 4, 256, 0, stream>>>(Kraw, ln_kv_g, ln_kv_b, Kbf);
  ln_bf16<<<KVROWS / 4, 256, 0, stream>>>(Vraw, ln_kv_g, ln_kv_b, Vbf);
  // 4) pack K and V^T into swizzled per-(b,slab,head,chunk) blocks
  pack_k<<<B_N * K_N * 9, 256, 0, stream>>>(Kbf, Kpk);
  pack_vt<<<B_N * K_N * 9, 256, 0, stream>>>(Vbf, Vtp);
  // 5) attention
  attn_kernel<<<9 * 16 * 4 * 2, 256, 0, stream>>>(
      Qbf, Kpk, Vtp, topo, lam, D0, slab, O);
  // 6) output projection + residual
  out_proj<<<QROWS / 64, 256, 0, stream>>>(O, Wp, F3, out);
}